// Round 1
// baseline (99325.134 us; speedup 1.0000x reference)
//
#include <hip/hip_runtime.h>
#include <hip/hip_cooperative_groups.h>

namespace cg = cooperative_groups;

#define T_    300
#define B_    16
#define S_    160
#define NMEL_ 80
#define PRE_  256
#define ENC_  512
#define ATT_  128
#define DIM_  1024
#define XSTR  1290   // LDS x-tile stride: 1290 % 32 = 10 -> 16 distinct banks for b=0..15

__device__ __forceinline__ float fexp2f(float x) { return __builtin_amdgcn_exp2f(x); }
__device__ __forceinline__ float fsigf(float x)  { return 1.0f / (1.0f + fexp2f(-1.442695041f * x)); }
__device__ __forceinline__ float ftanhf(float x) {
  float xc = fminf(fmaxf(x, -15.0f), 15.0f);
  float e = fexp2f(2.885390082f * xc);   // e^(2x)
  return (e - 1.0f) / (e + 1.0f);
}

// ---------------- prenet: mel_pre[t][b][256] for t=0..299 (frame 0 is the zero "go" frame)
__launch_bounds__(256)
__global__ void prenet_kernel(const float* __restrict__ mels,
                              const float* __restrict__ pW1, const float* __restrict__ pb1,
                              const float* __restrict__ pW2, const float* __restrict__ pb2,
                              float* __restrict__ melpre) {
  __shared__ float mcol[NMEL_];
  __shared__ float pcol[PRE_];
  const int b = blockIdx.x / 30;
  const int tbase = (blockIdx.x % 30) * 10;
  const int tid = threadIdx.x;
  for (int f = 0; f < 10; ++f) {
    const int t = tbase + f;
    if (tid < NMEL_) mcol[tid] = (t == 0) ? 0.0f : mels[(b*NMEL_ + tid)*T_ + (t-1)];
    __syncthreads();
    {
      float a1 = pb1[tid];
      const float* w1 = pW1 + tid*NMEL_;
      for (int m = 0; m < NMEL_; ++m) a1 += w1[m]*mcol[m];
      pcol[tid] = fmaxf(a1, 0.0f);
    }
    __syncthreads();
    {
      float a2 = pb2[tid];
      const float* w2 = pW2 + tid*PRE_;
      for (int d = 0; d < PRE_; d += 4) {
        const float4 wv = *(const float4*)(w2 + d);
        a2 += wv.x*pcol[d] + wv.y*pcol[d+1] + wv.z*pcol[d+2] + wv.w*pcol[d+3];
      }
      melpre[(t*B_ + b)*PRE_ + tid] = fmaxf(a2, 0.0f);
    }
    __syncthreads();
  }
}

// ---------------- init: broadcast LSTM states, effective conv weight Weff[a][k] = sum_l conv2[a][l]*conv1[l][k]
__launch_bounds__(256)
__global__ void init_kernel(const float* __restrict__ h0, const float* __restrict__ c0,
                            const float* __restrict__ conv1, const float* __restrict__ conv2,
                            float* __restrict__ h1buf, float* __restrict__ h0st,
                            float* __restrict__ c0s, float* __restrict__ c1s,
                            float* __restrict__ weff) {
  const int idx = blockIdx.x*256 + threadIdx.x;
  if (idx < B_*DIM_) {
    const int j = idx & (DIM_-1);
    h0st[idx]  = h0[j];
    h1buf[idx] = h0[DIM_ + j];   // slot 0 = h1 state for step t=0
    c0s[idx]   = c0[j];
    c1s[idx]   = c0[DIM_ + j];
  } else if (idx < B_*DIM_ + ATT_*32) {
    const int r = idx - B_*DIM_;
    const int a = r >> 5, k = r & 31;
    float acc = 0.0f;
    if (k < 31) {
      for (int l = 0; l < 32; ++l) acc += conv2[a*32 + l]*conv1[l*31 + k];
    }
    weff[r] = acc;               // stride 32, slot k=31 = 0 (never read)
  }
}

// ---------------- l_enc = enc_out @ Wt^T : [B][S][ATT]
__launch_bounds__(256)
__global__ void lenc_kernel(const float* __restrict__ enc, const float* __restrict__ Wt,
                            float* __restrict__ lencb) {
  __shared__ float es[4*ENC_];
  const int b = blockIdx.x / 40;
  const int s0 = (blockIdx.x % 40) * 4;
  const int tid = threadIdx.x;
  for (int idx = tid; idx < 4*ENC_; idx += 256) es[idx] = enc[(b*S_ + s0)*ENC_ + idx];
  __syncthreads();
  const int a = tid & 127, sh = tid >> 7;
  const float* w = Wt + a*ENC_;
  for (int p = 0; p < 2; ++p) {
    const int sl = sh*2 + p;
    const float* e = es + sl*ENC_;
    float acc = 0.0f;
    for (int j = 0; j < ENC_; j += 4) {
      const float4 wv = *(const float4*)(w + j);
      acc += wv.x*e[j] + wv.y*e[j+1] + wv.z*e[j+2] + wv.w*e[j+3];
    }
    lencb[(b*S_ + s0 + sl)*ATT_ + a] = acc;
  }
}

// ---------------- persistent cooperative decoder
// grid = 256 blocks x 512 threads, 3 grid syncs per step.
// P1: blk 0..15 attention(+proj t-1) | blk 16..143 gates0_pre (mel+h0 parts) | blk 144..255 gates1_pre (Whh1 part)
// P2: all blocks: gates0 align part (K=512) + LSTM0 activation -> h0
// P3: all blocks: gates1 h0 part (K=1024) + LSTM1 activation -> h1
__launch_bounds__(512, 2)
__global__ void decoder_kernel(
    const float* __restrict__ melpre, const float* __restrict__ lencb,
    const float* __restrict__ weff,
    float* __restrict__ h1buf, float* __restrict__ albuf,
    float* __restrict__ h0st, float* __restrict__ c0s, float* __restrict__ c1s,
    float* __restrict__ g0pre, float* __restrict__ g1pre,
    const float* __restrict__ enc, const int* __restrict__ tlen,
    const float* __restrict__ Wq, const float* __restrict__ wsc,
    const float* __restrict__ Wih0, const float* __restrict__ Whh0,
    const float* __restrict__ bih0, const float* __restrict__ bhh0,
    const float* __restrict__ Wih1, const float* __restrict__ Whh1,
    const float* __restrict__ bih1, const float* __restrict__ bhh1,
    const float* __restrict__ projW, const float* __restrict__ projb,
    float* __restrict__ out_mel, float* __restrict__ out_stop, float* __restrict__ out_attn)
{
  extern __shared__ float xt[];        // 16 x XSTR x-tile
  __shared__ float cum_p[S_ + 30];     // cumulative attention, 15-zero pads each side, persists all steps
  __shared__ float q_s[ATT_];
  __shared__ float spf[S_*4];
  __shared__ float score_s[S_];
  __shared__ float attn_s[S_];
  __shared__ float red_s[1];
  __shared__ float gv[256];

  cg::grid_group grid = cg::this_grid();
  const int blk = blockIdx.x;
  const int tid = threadIdx.x;

  if (blk < B_) {
    for (int i = tid; i < S_ + 30; i += 512) cum_p[i] = 0.0f;
  }
  const int mylen = (blk < B_) ? tlen[blk] : 0;
  __syncthreads();

  for (int t = 0; t < T_; ++t) {
    const int prev = t & 1;
    const int cur = prev ^ 1;

    //====================== P1 ======================
    if (blk < B_) {
      const int b = blk;
      // ---- q = h1_{t-1} @ Wq^T
      {
        const int a = tid & 127, part = tid >> 7;
        const float* hp = h1buf + prev*B_*DIM_ + b*DIM_ + part*256;
        const float* wq = Wq + a*DIM_ + part*256;
        float acc = 0.0f;
        for (int j = 0; j < 256; j += 4) {
          const float4 wv = *(const float4*)(wq + j);
          const float4 hv = *(const float4*)(hp + j);
          acc += wv.x*hv.x + wv.y*hv.y + wv.z*hv.z + wv.w*hv.w;
        }
        spf[a*4 + part] = acc;
      }
      __syncthreads();
      if (tid < ATT_) q_s[tid] = spf[tid*4] + spf[tid*4+1] + spf[tid*4+2] + spf[tid*4+3];
      __syncthreads();
      // ---- scores: score[s] = sum_a w[a]*tanh(q[a] + lenc[s][a] + sum_k Weff[a][k]*cum[s+k-15])
      {
        const int sl = tid & 127, ag = tid >> 7;
        for (int p = 0; p < 2; ++p) {
          const int s = sl + p*128;
          if (s < S_) {
            float cw[31];
            #pragma unroll
            for (int k = 0; k < 31; ++k) cw[k] = cum_p[s + k];
            const float* le = lencb + (b*S_ + s)*ATT_ + ag*32;
            float ps = 0.0f;
            for (int i = 0; i < 32; ++i) {
              const int a = ag*32 + i;
              const float* wk = weff + a*32;
              float loc = 0.0f;
              #pragma unroll
              for (int k = 0; k < 31; ++k) loc += wk[k]*cw[k];
              ps += wsc[a]*ftanhf(q_s[a] + le[i] + loc);
            }
            spf[s*4 + ag] = ps;
          }
        }
      }
      __syncthreads();
      if (tid < S_) {
        float sc = spf[tid*4] + spf[tid*4+1] + spf[tid*4+2] + spf[tid*4+3];
        if (tid >= mylen) sc = -1.0e30f;
        score_s[tid] = sc;
      }
      __syncthreads();
      // ---- softmax (wave 0)
      if (tid < 64) {
        float m = -1.0e30f;
        for (int i = tid; i < S_; i += 64) m = fmaxf(m, score_s[i]);
        #pragma unroll
        for (int o = 32; o > 0; o >>= 1) m = fmaxf(m, __shfl_xor(m, o, 64));
        float sum = 0.0f;
        for (int i = tid; i < S_; i += 64) {
          const float e = fexp2f(1.442695041f*(score_s[i] - m));
          score_s[i] = e;
          sum += e;
        }
        #pragma unroll
        for (int o = 32; o > 0; o >>= 1) sum += __shfl_xor(sum, o, 64);
        if (tid == 0) red_s[0] = sum;
      }
      __syncthreads();
      {
        const float inv = 1.0f / red_s[0];
        if (tid < S_) {
          const float av = score_s[tid]*inv;
          attn_s[tid] = av;
          cum_p[15 + tid] += av;
          out_attn[(b*S_ + tid)*T_ + t] = av;
        }
      }
      __syncthreads();
      // ---- align = attn @ enc_out  (512 threads <-> e)
      {
        const float* eb = enc + (b*S_)*ENC_ + tid;
        float acc = 0.0f;
        for (int s = 0; s < S_; ++s) acc += attn_s[s]*eb[s*ENC_];
        albuf[cur*B_*ENC_ + b*ENC_ + tid] = acc;
      }
      // ---- projection of step t-1 (h1_{t-1}, align_{t-1} both live in the "prev" slots)
      if (t > 0) {
        const int o = tid >> 2, part = tid & 3;
        if (o < 81) {
          const float* hp = h1buf + prev*B_*DIM_ + b*DIM_;
          const float* ap = albuf + prev*B_*ENC_ + b*ENC_;
          const float* w = projW + o*1536;
          const int j0 = part*384;
          float acc = 0.0f;
          for (int j = j0; j < j0 + 384; j += 4) {
            const float4 wv = *(const float4*)(w + j);
            float4 xv;
            if (j < DIM_) xv = *(const float4*)(hp + j);
            else          xv = *(const float4*)(ap + (j - DIM_));
            acc += wv.x*xv.x + wv.y*xv.y + wv.z*xv.z + wv.w*xv.w;
          }
          spf[o*4 + part] = acc;
        }
        __syncthreads();
        if (tid < 81) {
          const float v = projb[tid] + spf[tid*4] + spf[tid*4+1] + spf[tid*4+2] + spf[tid*4+3];
          if (tid < 80) out_mel[(b*NMEL_ + tid)*T_ + (t-1)] = v;
          else          out_stop[b*T_ + (t-1)] = v;
        }
      }
    } else if (blk < 144) {
      // ---- g0pre[b][n] = bih0+bhh0 + mel_t@Wih0[:,0:256] + h0@Whh0 ; 32 rows/block
      for (int idx = tid; idx < B_*1280; idx += 512) {
        const int bb = idx / 1280;
        const int j = idx - bb*1280;
        xt[bb*XSTR + j] = (j < 256) ? melpre[(t*B_ + bb)*PRE_ + j] : h0st[bb*DIM_ + (j - 256)];
      }
      __syncthreads();
      const int ks = tid & 63;
      const int bgb = ((tid >> 6) & 1)*8;
      const int rg = tid >> 7;
      const int nbase = (blk - 16)*32 + rg*8;
      float acc[8][8];
      #pragma unroll
      for (int ri = 0; ri < 8; ++ri)
        #pragma unroll
        for (int bi = 0; bi < 8; ++bi) acc[ri][bi] = 0.0f;
      { // K sub A: mel part, K=256, chunk=4 -> 1 quad
        const int j = ks*4;
        float4 w4[8];
        #pragma unroll
        for (int ri = 0; ri < 8; ++ri) w4[ri] = *(const float4*)(Wih0 + (nbase+ri)*768 + j);
        #pragma unroll
        for (int bi = 0; bi < 8; ++bi) {
          const float* xp = xt + (bgb+bi)*XSTR + j;
          const float x0 = xp[0], x1 = xp[1], x2 = xp[2], x3 = xp[3];
          #pragma unroll
          for (int ri = 0; ri < 8; ++ri)
            acc[ri][bi] += w4[ri].x*x0 + w4[ri].y*x1 + w4[ri].z*x2 + w4[ri].w*x3;
        }
      }
      #pragma unroll
      for (int q = 0; q < 4; ++q) { // K sub B: h0 part, K=1024, chunk=16 -> 4 quads
        const int j = ks*16 + q*4;
        float4 w4[8];
        #pragma unroll
        for (int ri = 0; ri < 8; ++ri) w4[ri] = *(const float4*)(Whh0 + (nbase+ri)*1024 + j);
        #pragma unroll
        for (int bi = 0; bi < 8; ++bi) {
          const float* xp = xt + (bgb+bi)*XSTR + 256 + j;
          const float x0 = xp[0], x1 = xp[1], x2 = xp[2], x3 = xp[3];
          #pragma unroll
          for (int ri = 0; ri < 8; ++ri)
            acc[ri][bi] += w4[ri].x*x0 + w4[ri].y*x1 + w4[ri].z*x2 + w4[ri].w*x3;
        }
      }
      #pragma unroll
      for (int ri = 0; ri < 8; ++ri)
        #pragma unroll
        for (int bi = 0; bi < 8; ++bi) {
          float v = acc[ri][bi];
          v += __shfl_down(v, 32, 64);
          v += __shfl_down(v, 16, 64);
          v += __shfl_down(v, 8, 64);
          v += __shfl_down(v, 4, 64);
          v += __shfl_down(v, 2, 64);
          v += __shfl_down(v, 1, 64);
          if (ks == 0) {
            const int n = nbase + ri;
            g0pre[(bgb+bi)*4096 + n] = bih0[n] + bhh0[n] + v;
          }
        }
    } else {
      // ---- g1pre[b][n] = bih1+bhh1 + h1_{t-1}@Whh1 ; 37 rows/block (guarded)
      for (int idx = tid; idx < B_*DIM_; idx += 512)
        xt[(idx >> 10)*XSTR + (idx & 1023)] = h1buf[prev*B_*DIM_ + idx];
      __syncthreads();
      const int rb = blk - 144;
      const int start = rb*37;
      const int cnt = (4096 - start < 37) ? (4096 - start) : 37;
      const int ks = tid & 63;
      const int bgb = ((tid >> 6) & 1)*8;
      const int rg = tid >> 7;
      for (int pass = 0; pass < 2; ++pass) {
        const int rbase = pass*32 + rg*8;
        if (rbase < cnt) {
          int nn[8];
          const float* wrow[8];
          #pragma unroll
          for (int ri = 0; ri < 8; ++ri) {
            const int r = rbase + ri;
            const int rcl = (r < cnt) ? r : (cnt - 1);
            nn[ri] = (r < cnt) ? (start + r) : -1;
            wrow[ri] = Whh1 + (start + rcl)*1024;
          }
          float acc[8][8];
          #pragma unroll
          for (int ri = 0; ri < 8; ++ri)
            #pragma unroll
            for (int bi = 0; bi < 8; ++bi) acc[ri][bi] = 0.0f;
          #pragma unroll
          for (int q = 0; q < 4; ++q) {
            const int j = ks*16 + q*4;
            float4 w4[8];
            #pragma unroll
            for (int ri = 0; ri < 8; ++ri) w4[ri] = *(const float4*)(wrow[ri] + j);
            #pragma unroll
            for (int bi = 0; bi < 8; ++bi) {
              const float* xp = xt + (bgb+bi)*XSTR + j;
              const float x0 = xp[0], x1 = xp[1], x2 = xp[2], x3 = xp[3];
              #pragma unroll
              for (int ri = 0; ri < 8; ++ri)
                acc[ri][bi] += w4[ri].x*x0 + w4[ri].y*x1 + w4[ri].z*x2 + w4[ri].w*x3;
            }
          }
          #pragma unroll
          for (int ri = 0; ri < 8; ++ri)
            #pragma unroll
            for (int bi = 0; bi < 8; ++bi) {
              float v = acc[ri][bi];
              v += __shfl_down(v, 32, 64);
              v += __shfl_down(v, 16, 64);
              v += __shfl_down(v, 8, 64);
              v += __shfl_down(v, 4, 64);
              v += __shfl_down(v, 2, 64);
              v += __shfl_down(v, 1, 64);
              if (ks == 0 && nn[ri] >= 0) {
                const int n = nn[ri];
                g1pre[(bgb+bi)*4096 + n] = bih1[n] + bhh1[n] + v;
              }
            }
        }
      }
    }
    grid.sync();

    //====================== P2: gates0 align part + LSTM0 ======================
    {
      for (int idx = tid; idx < B_*ENC_; idx += 512)
        xt[(idx >> 9)*XSTR + (idx & 511)] = albuf[cur*B_*ENC_ + idx];
      __syncthreads();
      const int ks = tid & 63;
      const int bgb = ((tid >> 6) & 1)*8;
      const int rg = tid >> 7;                 // rg == jl (j-offset within this block's 4 j's)
      const int j0 = blk*4;
      int nn[4];
      const float* wrow[4];
      #pragma unroll
      for (int ri = 0; ri < 4; ++ri) {         // ri == gate
        nn[ri] = ri*1024 + j0 + rg;
        wrow[ri] = Wih0 + nn[ri]*768 + 256;
      }
      float acc[4][8];
      #pragma unroll
      for (int ri = 0; ri < 4; ++ri)
        #pragma unroll
        for (int bi = 0; bi < 8; ++bi) acc[ri][bi] = 0.0f;
      #pragma unroll
      for (int q = 0; q < 2; ++q) {            // K=512, chunk=8 -> 2 quads
        const int j = ks*8 + q*4;
        float4 w4[4];
        #pragma unroll
        for (int ri = 0; ri < 4; ++ri) w4[ri] = *(const float4*)(wrow[ri] + j);
        #pragma unroll
        for (int bi = 0; bi < 8; ++bi) {
          const float* xp = xt + (bgb+bi)*XSTR + j;
          const float x0 = xp[0], x1 = xp[1], x2 = xp[2], x3 = xp[3];
          #pragma unroll
          for (int ri = 0; ri < 4; ++ri)
            acc[ri][bi] += w4[ri].x*x0 + w4[ri].y*x1 + w4[ri].z*x2 + w4[ri].w*x3;
        }
      }
      #pragma unroll
      for (int ri = 0; ri < 4; ++ri)
        #pragma unroll
        for (int bi = 0; bi < 8; ++bi) {
          float v = acc[ri][bi];
          v += __shfl_down(v, 32, 64);
          v += __shfl_down(v, 16, 64);
          v += __shfl_down(v, 8, 64);
          v += __shfl_down(v, 4, 64);
          v += __shfl_down(v, 2, 64);
          v += __shfl_down(v, 1, 64);
          if (ks == 0) gv[(rg*4 + ri)*16 + (bgb+bi)] = v;
        }
      __syncthreads();
      if (tid < 64) {
        const int jl = tid >> 4, b = tid & 15;
        const int j = blk*4 + jl;
        const float gi = gv[(jl*4+0)*16 + b] + g0pre[b*4096 + j];
        const float gf = gv[(jl*4+1)*16 + b] + g0pre[b*4096 + 1024 + j];
        const float gg = gv[(jl*4+2)*16 + b] + g0pre[b*4096 + 2048 + j];
        const float go = gv[(jl*4+3)*16 + b] + g0pre[b*4096 + 3072 + j];
        const float c = c0s[b*DIM_ + j];
        const float cn = fsigf(gf)*c + fsigf(gi)*ftanhf(gg);
        const float hn = fsigf(go)*ftanhf(cn);
        c0s[b*DIM_ + j] = cn;
        h0st[b*DIM_ + j] = hn;
      }
    }
    grid.sync();

    //====================== P3: gates1 h0 part + LSTM1 ======================
    {
      for (int idx = tid; idx < B_*DIM_; idx += 512)
        xt[(idx >> 10)*XSTR + (idx & 1023)] = h0st[idx];
      __syncthreads();
      const int ks = tid & 63;
      const int bgb = ((tid >> 6) & 1)*8;
      const int rg = tid >> 7;
      const int j0 = blk*4;
      int nn[4];
      const float* wrow[4];
      #pragma unroll
      for (int ri = 0; ri < 4; ++ri) {
        nn[ri] = ri*1024 + j0 + rg;
        wrow[ri] = Wih1 + nn[ri]*1024;
      }
      float acc[4][8];
      #pragma unroll
      for (int ri = 0; ri < 4; ++ri)
        #pragma unroll
        for (int bi = 0; bi < 8; ++bi) acc[ri][bi] = 0.0f;
      #pragma unroll
      for (int q = 0; q < 4; ++q) {            // K=1024, chunk=16 -> 4 quads
        const int j = ks*16 + q*4;
        float4 w4[4];
        #pragma unroll
        for (int ri = 0; ri < 4; ++ri) w4[ri] = *(const float4*)(wrow[ri] + j);
        #pragma unroll
        for (int bi = 0; bi < 8; ++bi) {
          const float* xp = xt + (bgb+bi)*XSTR + j;
          const float x0 = xp[0], x1 = xp[1], x2 = xp[2], x3 = xp[3];
          #pragma unroll
          for (int ri = 0; ri < 4; ++ri)
            acc[ri][bi] += w4[ri].x*x0 + w4[ri].y*x1 + w4[ri].z*x2 + w4[ri].w*x3;
        }
      }
      #pragma unroll
      for (int ri = 0; ri < 4; ++ri)
        #pragma unroll
        for (int bi = 0; bi < 8; ++bi) {
          float v = acc[ri][bi];
          v += __shfl_down(v, 32, 64);
          v += __shfl_down(v, 16, 64);
          v += __shfl_down(v, 8, 64);
          v += __shfl_down(v, 4, 64);
          v += __shfl_down(v, 2, 64);
          v += __shfl_down(v, 1, 64);
          if (ks == 0) gv[(rg*4 + ri)*16 + (bgb+bi)] = v;
        }
      __syncthreads();
      if (tid < 64) {
        const int jl = tid >> 4, b = tid & 15;
        const int j = blk*4 + jl;
        const float gi = gv[(jl*4+0)*16 + b] + g1pre[b*4096 + j];
        const float gf = gv[(jl*4+1)*16 + b] + g1pre[b*4096 + 1024 + j];
        const float gg = gv[(jl*4+2)*16 + b] + g1pre[b*4096 + 2048 + j];
        const float go = gv[(jl*4+3)*16 + b] + g1pre[b*4096 + 3072 + j];
        const float c = c1s[b*DIM_ + j];
        const float cn = fsigf(gf)*c + fsigf(gi)*ftanhf(gg);
        const float hn = fsigf(go)*ftanhf(cn);
        c1s[b*DIM_ + j] = cn;
        h1buf[cur*B_*DIM_ + b*DIM_ + j] = hn;
      }
    }
    grid.sync();
  }

  // ---- final projection for t = T_-1 (states for step 299 land in slot 0)
  if (blk < B_) {
    const int b = blk;
    const int o = tid >> 2, part = tid & 3;
    if (o < 81) {
      const float* hp = h1buf + b*DIM_;
      const float* ap = albuf + b*ENC_;
      const float* w = projW + o*1536;
      const int j0 = part*384;
      float acc = 0.0f;
      for (int j = j0; j < j0 + 384; j += 4) {
        const float4 wv = *(const float4*)(w + j);
        float4 xv;
        if (j < DIM_) xv = *(const float4*)(hp + j);
        else          xv = *(const float4*)(ap + (j - DIM_));
        acc += wv.x*xv.x + wv.y*xv.y + wv.z*xv.z + wv.w*xv.w;
      }
      spf[o*4 + part] = acc;
    }
    __syncthreads();
    if (tid < 81) {
      const float v = projb[tid] + spf[tid*4] + spf[tid*4+1] + spf[tid*4+2] + spf[tid*4+3];
      if (tid < 80) out_mel[(b*NMEL_ + tid)*T_ + (T_-1)] = v;
      else          out_stop[b*T_ + (T_-1)] = v;
    }
  }
}

extern "C" void kernel_launch(void* const* d_in, const int* in_sizes, int n_in,
                              void* d_out, int out_size, void* d_ws, size_t ws_size,
                              hipStream_t stream) {
  const float* mels  = (const float*)d_in[0];
  const float* enc   = (const float*)d_in[1];
  const int*   tlen  = (const int*)d_in[2];
  const float* Wt    = (const float*)d_in[3];
  const float* Wq    = (const float*)d_in[4];
  const float* wsc   = (const float*)d_in[5];
  const float* conv1 = (const float*)d_in[6];
  const float* conv2 = (const float*)d_in[7];
  const float* pW1   = (const float*)d_in[8];
  const float* pb1   = (const float*)d_in[9];
  const float* pW2   = (const float*)d_in[10];
  const float* pb2   = (const float*)d_in[11];
  const float* Wih0  = (const float*)d_in[12];
  const float* Whh0  = (const float*)d_in[13];
  const float* bih0  = (const float*)d_in[14];
  const float* bhh0  = (const float*)d_in[15];
  const float* Wih1  = (const float*)d_in[16];
  const float* Whh1  = (const float*)d_in[17];
  const float* bih1  = (const float*)d_in[18];
  const float* bhh1  = (const float*)d_in[19];
  const float* h0    = (const float*)d_in[20];
  const float* c0    = (const float*)d_in[21];
  const float* projW = (const float*)d_in[22];
  const float* projb = (const float*)d_in[23];

  float* ws     = (float*)d_ws;       // total use: ~1.79M floats (~7.2 MB)
  float* melpre = ws;                 // 300*16*256
  float* lencb  = melpre + 1228800;   // 16*160*128
  float* weff   = lencb + 327680;     // 128*32
  float* h1buf  = weff + 4096;        // 2*16*1024 ping-pong
  float* albuf  = h1buf + 32768;      // 2*16*512 ping-pong
  float* h0st   = albuf + 16384;      // 16*1024
  float* c0s    = h0st + 16384;       // 16*1024
  float* c1s    = c0s + 16384;        // 16*1024
  float* g0pre  = c1s + 16384;        // 16*4096
  float* g1pre  = g0pre + 65536;      // 16*4096

  float* out_mel  = (float*)d_out;                  // [16][80][300]
  float* out_stop = out_mel + 384000;               // [16][300]
  float* out_attn = out_stop + 4800;                // [16][160][300]

  prenet_kernel<<<dim3(480), dim3(256), 0, stream>>>(mels, pW1, pb1, pW2, pb2, melpre);
  init_kernel<<<dim3(80), dim3(256), 0, stream>>>(h0, c0, conv1, conv2, h1buf, h0st, c0s, c1s, weff);
  lenc_kernel<<<dim3(640), dim3(256), 0, stream>>>(enc, Wt, lencb);

  void* args[] = {
    (void*)&melpre, (void*)&lencb, (void*)&weff, (void*)&h1buf, (void*)&albuf,
    (void*)&h0st, (void*)&c0s, (void*)&c1s, (void*)&g0pre, (void*)&g1pre,
    (void*)&enc, (void*)&tlen, (void*)&Wq, (void*)&wsc,
    (void*)&Wih0, (void*)&Whh0, (void*)&bih0, (void*)&bhh0,
    (void*)&Wih1, (void*)&Whh1, (void*)&bih1, (void*)&bhh1,
    (void*)&projW, (void*)&projb,
    (void*)&out_mel, (void*)&out_stop, (void*)&out_attn
  };
  hipLaunchCooperativeKernel((const void*)decoder_kernel, dim3(256), dim3(512),
                             args, (unsigned int)(B_*XSTR*sizeof(float)), stream);
}

// Round 2
// 66394.550 us; speedup vs baseline: 1.4960x; 1.4960x over previous
//
#include <hip/hip_runtime.h>

#define T_    300
#define B_    16
#define S_    160
#define NMEL_ 80
#define PRE_  256
#define ENC_  512
#define ATT_  128
#define DIM_  1024
#define XSTR  1284   // LDS x-tile stride (multiple of 4 for b128 alignment)

typedef unsigned int u32;

__device__ __forceinline__ float fexp2f(float x) { return __builtin_amdgcn_exp2f(x); }
__device__ __forceinline__ float fsigf(float x)  { return 1.0f / (1.0f + fexp2f(-1.442695041f * x)); }
__device__ __forceinline__ float ftanhf(float x) {
  float xc = fminf(fmaxf(x, -15.0f), 15.0f);
  float e = fexp2f(2.885390082f * xc);   // e^(2x)
  return (e - 1.0f) / (e + 1.0f);
}

// ---- system-scope (LLC-coherent, L1/L2-bypass) accessors for mutable cross-block state
__device__ __forceinline__ float4 ld1q_sys(const float* p) {
  float4 v;
  asm volatile("global_load_dwordx4 %0, %1, off sc0 sc1\n\ts_waitcnt vmcnt(0)"
               : "=v"(v) : "v"(p) : "memory");
  return v;
}
__device__ __forceinline__ void ld4q_sys(const float* p0, const float* p1,
                                         const float* p2, const float* p3,
                                         float4& a, float4& b, float4& c, float4& d) {
  asm volatile(
      "global_load_dwordx4 %0, %4, off sc0 sc1\n\t"
      "global_load_dwordx4 %1, %5, off sc0 sc1\n\t"
      "global_load_dwordx4 %2, %6, off sc0 sc1\n\t"
      "global_load_dwordx4 %3, %7, off sc0 sc1\n\t"
      "s_waitcnt vmcnt(0)"
      : "=&v"(a), "=&v"(b), "=&v"(c), "=&v"(d)
      : "v"(p0), "v"(p1), "v"(p2), "v"(p3) : "memory");
}
__device__ __forceinline__ void ld4d_sys(const float* p0, const float* p1,
                                         const float* p2, const float* p3,
                                         float& a, float& b, float& c, float& d) {
  asm volatile(
      "global_load_dword %0, %4, off sc0 sc1\n\t"
      "global_load_dword %1, %5, off sc0 sc1\n\t"
      "global_load_dword %2, %6, off sc0 sc1\n\t"
      "global_load_dword %3, %7, off sc0 sc1\n\t"
      "s_waitcnt vmcnt(0)"
      : "=&v"(a), "=&v"(b), "=&v"(c), "=&v"(d)
      : "v"(p0), "v"(p1), "v"(p2), "v"(p3) : "memory");
}
__device__ __forceinline__ void st_sys(float* p, float v) {
  asm volatile("global_store_dword %0, %1, off sc0 sc1" :: "v"(p), "v"(v) : "memory");
}

// ---- lean grid barrier: no L2 flushes. All mutable shared data goes through sc0/sc1
// (LLC) so a per-wave vmcnt(0) drain + LLC atomics give correct cross-XCD ordering.
__device__ __forceinline__ void gridbar(u32* bar, int tid, int nblk) {
  asm volatile("s_waitcnt vmcnt(0)" ::: "memory");  // every wave drains its sc1 stores
  __syncthreads();
  if (tid == 0) {
    u32 g = __hip_atomic_load(&bar[1], __ATOMIC_RELAXED, __HIP_MEMORY_SCOPE_AGENT);
    u32 old = __hip_atomic_fetch_add(&bar[0], 1u, __ATOMIC_RELAXED, __HIP_MEMORY_SCOPE_AGENT);
    if (old == (u32)(nblk - 1)) {
      __hip_atomic_store(&bar[0], 0u, __ATOMIC_RELAXED, __HIP_MEMORY_SCOPE_AGENT);
      asm volatile("s_waitcnt vmcnt(0)" ::: "memory");  // reset lands before gen flips
      __hip_atomic_store(&bar[1], g + 1u, __ATOMIC_RELAXED, __HIP_MEMORY_SCOPE_AGENT);
    } else {
      while (__hip_atomic_load(&bar[1], __ATOMIC_RELAXED, __HIP_MEMORY_SCOPE_AGENT) == g) {
        __builtin_amdgcn_s_sleep(1);
      }
    }
  }
  __syncthreads();
}

// ---------------- prenet: mel_pre[t][b][256], frame 0 is the zero "go" frame
__launch_bounds__(256)
__global__ void prenet_kernel(const float* __restrict__ mels,
                              const float* __restrict__ pW1, const float* __restrict__ pb1,
                              const float* __restrict__ pW2, const float* __restrict__ pb2,
                              float* __restrict__ melpre) {
  __shared__ float mcol[NMEL_];
  __shared__ float pcol[PRE_];
  const int b = blockIdx.x / 30;
  const int tbase = (blockIdx.x % 30) * 10;
  const int tid = threadIdx.x;
  for (int f = 0; f < 10; ++f) {
    const int t = tbase + f;
    if (tid < NMEL_) mcol[tid] = (t == 0) ? 0.0f : mels[(b*NMEL_ + tid)*T_ + (t-1)];
    __syncthreads();
    {
      float a1 = pb1[tid];
      const float* w1 = pW1 + tid*NMEL_;
      for (int m = 0; m < NMEL_; ++m) a1 += w1[m]*mcol[m];
      pcol[tid] = fmaxf(a1, 0.0f);
    }
    __syncthreads();
    {
      float a2 = pb2[tid];
      const float* w2 = pW2 + tid*PRE_;
      for (int d = 0; d < PRE_; d += 4) {
        const float4 wv = *(const float4*)(w2 + d);
        a2 += wv.x*pcol[d] + wv.y*pcol[d+1] + wv.z*pcol[d+2] + wv.w*pcol[d+3];
      }
      melpre[(t*B_ + b)*PRE_ + tid] = fmaxf(a2, 0.0f);
    }
    __syncthreads();
  }
}

// ---------------- init: states, Weff, barrier counters
__launch_bounds__(256)
__global__ void init_kernel(const float* __restrict__ h0, const float* __restrict__ c0,
                            const float* __restrict__ conv1, const float* __restrict__ conv2,
                            float* __restrict__ h1buf, float* __restrict__ h0st,
                            float* __restrict__ c0s, float* __restrict__ c1s,
                            float* __restrict__ weff, u32* __restrict__ bar) {
  const int idx = blockIdx.x*256 + threadIdx.x;
  if (blockIdx.x == 0 && threadIdx.x < 16) bar[threadIdx.x] = 0u;
  if (idx < B_*DIM_) {
    const int j = idx & (DIM_-1);
    h0st[idx]  = h0[j];
    h1buf[idx] = h0[DIM_ + j];   // slot 0 = h1 state entering step t=0
    c0s[idx]   = c0[j];
    c1s[idx]   = c0[DIM_ + j];
  } else if (idx < B_*DIM_ + ATT_*32) {
    const int r = idx - B_*DIM_;
    const int a = r >> 5, k = r & 31;
    float acc = 0.0f;
    if (k < 31) {
      for (int l = 0; l < 32; ++l) acc += conv2[a*32 + l]*conv1[l*31 + k];
    }
    weff[r] = acc;
  }
}

// ---------------- l_enc = enc_out @ Wt^T : [B][S][ATT]
__launch_bounds__(256)
__global__ void lenc_kernel(const float* __restrict__ enc, const float* __restrict__ Wt,
                            float* __restrict__ lencb) {
  __shared__ float es[4*ENC_];
  const int b = blockIdx.x / 40;
  const int s0 = (blockIdx.x % 40) * 4;
  const int tid = threadIdx.x;
  for (int idx = tid; idx < 4*ENC_; idx += 256) es[idx] = enc[(b*S_ + s0)*ENC_ + idx];
  __syncthreads();
  const int a = tid & 127, sh = tid >> 7;
  const float* w = Wt + a*ENC_;
  for (int p = 0; p < 2; ++p) {
    const int sl = sh*2 + p;
    const float* e = es + sl*ENC_;
    float acc = 0.0f;
    for (int j = 0; j < ENC_; j += 4) {
      const float4 wv = *(const float4*)(w + j);
      acc += wv.x*e[j] + wv.y*e[j+1] + wv.z*e[j+2] + wv.w*e[j+3];
    }
    lencb[(b*S_ + s0 + sl)*ATT_ + a] = acc;
  }
}

// ---------------- persistent decoder, custom barrier, 3 syncs/step
// P1: blk 0..15 attention(+proj t-1) | blk 16..143 gates0_pre | blk 144..255 gates1_pre
// P2: all: gates0 align part (K=512) + LSTM0 act
// P3: all: gates1 h0 part (K=1024) + LSTM1 act
__launch_bounds__(512, 2)
__global__ void decoder_kernel(
    const float* __restrict__ melpre, const float* __restrict__ lencb,
    const float* __restrict__ weff,
    float* __restrict__ h1buf, float* __restrict__ albuf,
    float* __restrict__ h0st, float* __restrict__ c0s, float* __restrict__ c1s,
    float* __restrict__ g0pre, float* __restrict__ g1pre, u32* __restrict__ bar,
    const float* __restrict__ enc, const int* __restrict__ tlen,
    const float* __restrict__ Wq, const float* __restrict__ wsc,
    const float* __restrict__ Wih0, const float* __restrict__ Whh0,
    const float* __restrict__ bih0, const float* __restrict__ bhh0,
    const float* __restrict__ Wih1, const float* __restrict__ Whh1,
    const float* __restrict__ bih1, const float* __restrict__ bhh1,
    const float* __restrict__ projW, const float* __restrict__ projb,
    float* __restrict__ out_mel, float* __restrict__ out_stop, float* __restrict__ out_attn)
{
  extern __shared__ float xt[];        // GEMV blocks: 16 x XSTR x-tile. attn blocks: h1prev[1024] | alignprev[512]
  __shared__ float cum_p[S_ + 30];
  __shared__ float q_s[ATT_];
  __shared__ float spf[S_*4];
  __shared__ float score_s[S_];
  __shared__ float attn_s[S_];
  __shared__ float red_s[1];
  __shared__ float gv[256];

  const int blk = blockIdx.x;
  const int tid = threadIdx.x;
  const int nblk = gridDim.x;

  if (blk < B_) {
    for (int i = tid; i < S_ + 30; i += 512) cum_p[i] = 0.0f;
  }
  const int mylen = (blk < B_) ? tlen[blk] : 0;
  __syncthreads();

  const int ks = tid & 63;
  const int bgb = ((tid >> 6) & 1)*8;
  const int rg = tid >> 7;

  for (int t = 0; t < T_; ++t) {
    const int prev = t & 1;
    const int cur = prev ^ 1;

    //====================== P1 ======================
    if (blk < B_) {
      const int b = blk;
      // stage h1_{t-1}[b] (1024 f) and align_{t-1}[b] (512 f) into LDS via LLC path
      if (tid < 256) {
        float4 v = ld1q_sys(h1buf + prev*B_*DIM_ + b*DIM_ + tid*4);
        *(float4*)(xt + tid*4) = v;
      } else if (tid < 384) {
        const int j = tid - 256;
        float4 v = ld1q_sys(albuf + prev*B_*ENC_ + b*ENC_ + j*4);
        *(float4*)(xt + DIM_ + j*4) = v;
      }
      __syncthreads();
      // ---- q = h1_{t-1} @ Wq^T  (4-way K split)
      {
        const int a = tid & 127, part = tid >> 7;
        const float* hp = xt + part*256;
        const float* wq = Wq + a*DIM_ + part*256;
        float acc = 0.0f;
        for (int j = 0; j < 256; j += 4) {
          const float4 wv = *(const float4*)(wq + j);
          const float4 hv = *(const float4*)(hp + j);
          acc += wv.x*hv.x + wv.y*hv.y + wv.z*hv.z + wv.w*hv.w;
        }
        spf[a*4 + part] = acc;
      }
      __syncthreads();
      if (tid < ATT_) q_s[tid] = spf[tid*4] + spf[tid*4+1] + spf[tid*4+2] + spf[tid*4+3];
      __syncthreads();
      // ---- scores
      {
        const int sl = tid & 127, ag = tid >> 7;
        for (int p = 0; p < 2; ++p) {
          const int s = sl + p*128;
          if (s < S_) {
            float cw[31];
            #pragma unroll
            for (int k = 0; k < 31; ++k) cw[k] = cum_p[s + k];
            const float* le = lencb + (b*S_ + s)*ATT_ + ag*32;
            float ps = 0.0f;
            for (int i = 0; i < 32; ++i) {
              const int a = ag*32 + i;
              const float* wk = weff + a*32;
              float loc = 0.0f;
              #pragma unroll
              for (int k = 0; k < 31; ++k) loc += wk[k]*cw[k];
              ps += wsc[a]*ftanhf(q_s[a] + le[i] + loc);
            }
            spf[s*4 + ag] = ps;
          }
        }
      }
      __syncthreads();
      if (tid < S_) {
        float sc = spf[tid*4] + spf[tid*4+1] + spf[tid*4+2] + spf[tid*4+3];
        if (tid >= mylen) sc = -1.0e30f;
        score_s[tid] = sc;
      }
      __syncthreads();
      if (tid < 64) {
        float m = -1.0e30f;
        for (int i = tid; i < S_; i += 64) m = fmaxf(m, score_s[i]);
        #pragma unroll
        for (int o = 32; o > 0; o >>= 1) m = fmaxf(m, __shfl_xor(m, o, 64));
        float sum = 0.0f;
        for (int i = tid; i < S_; i += 64) {
          const float e = fexp2f(1.442695041f*(score_s[i] - m));
          score_s[i] = e;
          sum += e;
        }
        #pragma unroll
        for (int o = 32; o > 0; o >>= 1) sum += __shfl_xor(sum, o, 64);
        if (tid == 0) red_s[0] = sum;
      }
      __syncthreads();
      {
        const float inv = 1.0f / red_s[0];
        if (tid < S_) {
          const float av = score_s[tid]*inv;
          attn_s[tid] = av;
          cum_p[15 + tid] += av;
          out_attn[(b*S_ + tid)*T_ + t] = av;
        }
      }
      __syncthreads();
      // ---- align = attn @ enc_out
      {
        const float* eb = enc + (b*S_)*ENC_ + tid;
        float acc = 0.0f;
        for (int s = 0; s < S_; ++s) acc += attn_s[s]*eb[s*ENC_];
        st_sys(albuf + cur*B_*ENC_ + b*ENC_ + tid, acc);
      }
      // ---- projection of step t-1 from staged LDS copies
      if (t > 0) {
        const int o = tid >> 2, part = tid & 3;
        if (o < 81) {
          const float* w = projW + o*1536;
          const int j0 = part*384;
          float acc = 0.0f;
          for (int j = j0; j < j0 + 384; j += 4) {
            const float4 wv = *(const float4*)(w + j);
            const float4 xv = *(const float4*)(xt + j);   // [h1prev | alignprev] laid out contiguously
            acc += wv.x*xv.x + wv.y*xv.y + wv.z*xv.z + wv.w*xv.w;
          }
          spf[o*4 + part] = acc;
        }
        __syncthreads();
        if (tid < 81) {
          const float v = projb[tid] + spf[tid*4] + spf[tid*4+1] + spf[tid*4+2] + spf[tid*4+3];
          if (tid < 80) out_mel[(b*NMEL_ + tid)*T_ + (t-1)] = v;
          else          out_stop[b*T_ + (t-1)] = v;
        }
      }
    } else if (blk < 144) {
      // ---- g0pre: mel part (Wih0[:, :256]) + Whh0 @ h0 ; 32 rows/block
      // stage mel (normal, read-only) and h0 (LLC path)
      for (int idx = tid; idx < 1024; idx += 512) {           // 16 x 256 = 1024 quads? no: 4096 floats = 1024 quads
        const int bb = idx >> 6, jq = idx & 63;
        float4 v = *(const float4*)(melpre + (t*B_)*PRE_ + idx*4);
        *(float4*)(xt + bb*XSTR + jq*4) = v;
      }
      {
        float4 va, vb, vc, vd;
        #pragma unroll
        for (int g = 0; g < 2; ++g) {                          // 4096 quads of h0: 8 per thread
          const int i0 = tid + (g*4+0)*512, i1 = tid + (g*4+1)*512,
                    i2 = tid + (g*4+2)*512, i3 = tid + (g*4+3)*512;
          ld4q_sys(h0st + i0*4, h0st + i1*4, h0st + i2*4, h0st + i3*4, va, vb, vc, vd);
          *(float4*)(xt + (i0 >> 8)*XSTR + 256 + (i0 & 255)*4) = va;
          *(float4*)(xt + (i1 >> 8)*XSTR + 256 + (i1 & 255)*4) = vb;
          *(float4*)(xt + (i2 >> 8)*XSTR + 256 + (i2 & 255)*4) = vc;
          *(float4*)(xt + (i3 >> 8)*XSTR + 256 + (i3 & 255)*4) = vd;
        }
      }
      __syncthreads();
      const int nbase = (blk - 16)*32 + rg*8;
      float acc[8][8];
      #pragma unroll
      for (int ri = 0; ri < 8; ++ri)
        #pragma unroll
        for (int bi = 0; bi < 8; ++bi) acc[ri][bi] = 0.0f;
      { // mel part: lane ks covers j = ks*4 (contiguous across lanes)
        const int j = ks*4;
        float4 w4[8];
        #pragma unroll
        for (int ri = 0; ri < 8; ++ri) w4[ri] = *(const float4*)(Wih0 + (nbase+ri)*768 + j);
        #pragma unroll
        for (int bi = 0; bi < 8; ++bi) {
          const float4 xv = *(const float4*)(xt + (bgb+bi)*XSTR + j);
          #pragma unroll
          for (int ri = 0; ri < 8; ++ri)
            acc[ri][bi] += w4[ri].x*xv.x + w4[ri].y*xv.y + w4[ri].z*xv.z + w4[ri].w*xv.w;
        }
      }
      #pragma unroll
      for (int q = 0; q < 4; ++q) { // h0 part: j = q*256 + ks*4
        const int j = q*256 + ks*4;
        float4 w4[8];
        #pragma unroll
        for (int ri = 0; ri < 8; ++ri) w4[ri] = *(const float4*)(Whh0 + (nbase+ri)*1024 + j);
        #pragma unroll
        for (int bi = 0; bi < 8; ++bi) {
          const float4 xv = *(const float4*)(xt + (bgb+bi)*XSTR + 256 + j);
          #pragma unroll
          for (int ri = 0; ri < 8; ++ri)
            acc[ri][bi] += w4[ri].x*xv.x + w4[ri].y*xv.y + w4[ri].z*xv.z + w4[ri].w*xv.w;
        }
      }
      #pragma unroll
      for (int ri = 0; ri < 8; ++ri)
        #pragma unroll
        for (int bi = 0; bi < 8; ++bi) {
          float v = acc[ri][bi];
          v += __shfl_down(v, 32, 64);
          v += __shfl_down(v, 16, 64);
          v += __shfl_down(v, 8, 64);
          v += __shfl_down(v, 4, 64);
          v += __shfl_down(v, 2, 64);
          v += __shfl_down(v, 1, 64);
          if (ks == 0) {
            const int n = nbase + ri;
            st_sys(g0pre + (bgb+bi)*4096 + n, bih0[n] + bhh0[n] + v);
          }
        }
    } else {
      // ---- g1pre: Whh1 @ h1_{t-1} ; 37 rows/block (guarded)
      {
        float4 va, vb, vc, vd;
        const float* src = h1buf + prev*B_*DIM_;
        #pragma unroll
        for (int g = 0; g < 2; ++g) {
          const int i0 = tid + (g*4+0)*512, i1 = tid + (g*4+1)*512,
                    i2 = tid + (g*4+2)*512, i3 = tid + (g*4+3)*512;
          ld4q_sys(src + i0*4, src + i1*4, src + i2*4, src + i3*4, va, vb, vc, vd);
          *(float4*)(xt + (i0 >> 8)*XSTR + (i0 & 255)*4) = va;
          *(float4*)(xt + (i1 >> 8)*XSTR + (i1 & 255)*4) = vb;
          *(float4*)(xt + (i2 >> 8)*XSTR + (i2 & 255)*4) = vc;
          *(float4*)(xt + (i3 >> 8)*XSTR + (i3 & 255)*4) = vd;
        }
      }
      __syncthreads();
      const int rb = blk - 144;
      const int start = rb*37;
      const int cnt = (4096 - start < 37) ? (4096 - start) : 37;
      for (int pass = 0; pass < 2; ++pass) {
        const int rbase = pass*32 + rg*8;
        if (rbase < cnt) {
          int nn[8];
          const float* wrow[8];
          #pragma unroll
          for (int ri = 0; ri < 8; ++ri) {
            const int r = rbase + ri;
            const int rcl = (r < cnt) ? r : (cnt - 1);
            nn[ri] = (r < cnt) ? (start + r) : -1;
            wrow[ri] = Whh1 + (start + rcl)*1024;
          }
          float acc[8][8];
          #pragma unroll
          for (int ri = 0; ri < 8; ++ri)
            #pragma unroll
            for (int bi = 0; bi < 8; ++bi) acc[ri][bi] = 0.0f;
          #pragma unroll
          for (int q = 0; q < 4; ++q) {
            const int j = q*256 + ks*4;
            float4 w4[8];
            #pragma unroll
            for (int ri = 0; ri < 8; ++ri) w4[ri] = *(const float4*)(wrow[ri] + j);
            #pragma unroll
            for (int bi = 0; bi < 8; ++bi) {
              const float4 xv = *(const float4*)(xt + (bgb+bi)*XSTR + j);
              #pragma unroll
              for (int ri = 0; ri < 8; ++ri)
                acc[ri][bi] += w4[ri].x*xv.x + w4[ri].y*xv.y + w4[ri].z*xv.z + w4[ri].w*xv.w;
            }
          }
          #pragma unroll
          for (int ri = 0; ri < 8; ++ri)
            #pragma unroll
            for (int bi = 0; bi < 8; ++bi) {
              float v = acc[ri][bi];
              v += __shfl_down(v, 32, 64);
              v += __shfl_down(v, 16, 64);
              v += __shfl_down(v, 8, 64);
              v += __shfl_down(v, 4, 64);
              v += __shfl_down(v, 2, 64);
              v += __shfl_down(v, 1, 64);
              if (ks == 0 && nn[ri] >= 0) {
                const int n = nn[ri];
                st_sys(g1pre + (bgb+bi)*4096 + n, bih1[n] + bhh1[n] + v);
              }
            }
        }
      }
    }
    gridbar(bar, tid, nblk);

    //====================== P2: gates0 align part + LSTM0 ======================
    {
      { // stage align: 16 x 512 = 2048 quads, 4/thread
        float4 va, vb, vc, vd;
        const float* src = albuf + cur*B_*ENC_;
        const int i0 = tid, i1 = tid + 512, i2 = tid + 1024, i3 = tid + 1536;
        ld4q_sys(src + i0*4, src + i1*4, src + i2*4, src + i3*4, va, vb, vc, vd);
        *(float4*)(xt + (i0 >> 7)*XSTR + (i0 & 127)*4) = va;
        *(float4*)(xt + (i1 >> 7)*XSTR + (i1 & 127)*4) = vb;
        *(float4*)(xt + (i2 >> 7)*XSTR + (i2 & 127)*4) = vc;
        *(float4*)(xt + (i3 >> 7)*XSTR + (i3 & 127)*4) = vd;
      }
      __syncthreads();
      const int j0 = blk*4;
      const float* wrow[4];
      #pragma unroll
      for (int ri = 0; ri < 4; ++ri) wrow[ri] = Wih0 + (ri*1024 + j0 + rg)*768 + 256;
      float acc[4][8];
      #pragma unroll
      for (int ri = 0; ri < 4; ++ri)
        #pragma unroll
        for (int bi = 0; bi < 8; ++bi) acc[ri][bi] = 0.0f;
      #pragma unroll
      for (int q = 0; q < 2; ++q) {
        const int j = q*256 + ks*4;
        float4 w4[4];
        #pragma unroll
        for (int ri = 0; ri < 4; ++ri) w4[ri] = *(const float4*)(wrow[ri] + j);
        #pragma unroll
        for (int bi = 0; bi < 8; ++bi) {
          const float4 xv = *(const float4*)(xt + (bgb+bi)*XSTR + j);
          #pragma unroll
          for (int ri = 0; ri < 4; ++ri)
            acc[ri][bi] += w4[ri].x*xv.x + w4[ri].y*xv.y + w4[ri].z*xv.z + w4[ri].w*xv.w;
        }
      }
      #pragma unroll
      for (int ri = 0; ri < 4; ++ri)
        #pragma unroll
        for (int bi = 0; bi < 8; ++bi) {
          float v = acc[ri][bi];
          v += __shfl_down(v, 32, 64);
          v += __shfl_down(v, 16, 64);
          v += __shfl_down(v, 8, 64);
          v += __shfl_down(v, 4, 64);
          v += __shfl_down(v, 2, 64);
          v += __shfl_down(v, 1, 64);
          if (ks == 0) gv[(rg*4 + ri)*16 + (bgb+bi)] = v;
        }
      __syncthreads();
      if (tid < 64) {
        const int jl = tid >> 4, b = tid & 15;
        const int j = blk*4 + jl;
        const float* gp = g0pre + b*4096 + j;
        float pi, pf, pg, po;
        ld4d_sys(gp, gp + 1024, gp + 2048, gp + 3072, pi, pf, pg, po);
        const float gi = gv[(jl*4+0)*16 + b] + pi;
        const float gf = gv[(jl*4+1)*16 + b] + pf;
        const float gg = gv[(jl*4+2)*16 + b] + pg;
        const float go = gv[(jl*4+3)*16 + b] + po;
        const float c = c0s[b*DIM_ + j];
        const float cn = fsigf(gf)*c + fsigf(gi)*ftanhf(gg);
        const float hn = fsigf(go)*ftanhf(cn);
        c0s[b*DIM_ + j] = cn;                 // block-private: normal store
        st_sys(h0st + b*DIM_ + j, hn);        // cross-block: LLC store
      }
    }
    gridbar(bar, tid, nblk);

    //====================== P3: gates1 h0 part + LSTM1 ======================
    {
      {
        float4 va, vb, vc, vd;
        #pragma unroll
        for (int g = 0; g < 2; ++g) {
          const int i0 = tid + (g*4+0)*512, i1 = tid + (g*4+1)*512,
                    i2 = tid + (g*4+2)*512, i3 = tid + (g*4+3)*512;
          ld4q_sys(h0st + i0*4, h0st + i1*4, h0st + i2*4, h0st + i3*4, va, vb, vc, vd);
          *(float4*)(xt + (i0 >> 8)*XSTR + (i0 & 255)*4) = va;
          *(float4*)(xt + (i1 >> 8)*XSTR + (i1 & 255)*4) = vb;
          *(float4*)(xt + (i2 >> 8)*XSTR + (i2 & 255)*4) = vc;
          *(float4*)(xt + (i3 >> 8)*XSTR + (i3 & 255)*4) = vd;
        }
      }
      __syncthreads();
      const int j0 = blk*4;
      const float* wrow[4];
      #pragma unroll
      for (int ri = 0; ri < 4; ++ri) wrow[ri] = Wih1 + (ri*1024 + j0 + rg)*1024;
      float acc[4][8];
      #pragma unroll
      for (int ri = 0; ri < 4; ++ri)
        #pragma unroll
        for (int bi = 0; bi < 8; ++bi) acc[ri][bi] = 0.0f;
      #pragma unroll
      for (int q = 0; q < 4; ++q) {
        const int j = q*256 + ks*4;
        float4 w4[4];
        #pragma unroll
        for (int ri = 0; ri < 4; ++ri) w4[ri] = *(const float4*)(wrow[ri] + j);
        #pragma unroll
        for (int bi = 0; bi < 8; ++bi) {
          const float4 xv = *(const float4*)(xt + (bgb+bi)*XSTR + j);
          #pragma unroll
          for (int ri = 0; ri < 4; ++ri)
            acc[ri][bi] += w4[ri].x*xv.x + w4[ri].y*xv.y + w4[ri].z*xv.z + w4[ri].w*xv.w;
        }
      }
      #pragma unroll
      for (int ri = 0; ri < 4; ++ri)
        #pragma unroll
        for (int bi = 0; bi < 8; ++bi) {
          float v = acc[ri][bi];
          v += __shfl_down(v, 32, 64);
          v += __shfl_down(v, 16, 64);
          v += __shfl_down(v, 8, 64);
          v += __shfl_down(v, 4, 64);
          v += __shfl_down(v, 2, 64);
          v += __shfl_down(v, 1, 64);
          if (ks == 0) gv[(rg*4 + ri)*16 + (bgb+bi)] = v;
        }
      __syncthreads();
      if (tid < 64) {
        const int jl = tid >> 4, b = tid & 15;
        const int j = blk*4 + jl;
        const float* gp = g1pre + b*4096 + j;
        float pi, pf, pg, po;
        ld4d_sys(gp, gp + 1024, gp + 2048, gp + 3072, pi, pf, pg, po);
        const float gi = gv[(jl*4+0)*16 + b] + pi;
        const float gf = gv[(jl*4+1)*16 + b] + pf;
        const float gg = gv[(jl*4+2)*16 + b] + pg;
        const float go = gv[(jl*4+3)*16 + b] + po;
        const float c = c1s[b*DIM_ + j];
        const float cn = fsigf(gf)*c + fsigf(gi)*ftanhf(gg);
        const float hn = fsigf(go)*ftanhf(cn);
        c1s[b*DIM_ + j] = cn;
        st_sys(h1buf + cur*B_*DIM_ + b*DIM_ + j, hn);
      }
    }
    gridbar(bar, tid, nblk);
  }

  // ---- final projection for t = T_-1 (slot 0 holds step-299 h1/align)
  if (blk < B_) {
    const int b = blk;
    if (tid < 256) {
      float4 v = ld1q_sys(h1buf + b*DIM_ + tid*4);
      *(float4*)(xt + tid*4) = v;
    } else if (tid < 384) {
      const int j = tid - 256;
      float4 v = ld1q_sys(albuf + b*ENC_ + j*4);
      *(float4*)(xt + DIM_ + j*4) = v;
    }
    __syncthreads();
    const int o = tid >> 2, part = tid & 3;
    if (o < 81) {
      const float* w = projW + o*1536;
      const int j0 = part*384;
      float acc = 0.0f;
      for (int j = j0; j < j0 + 384; j += 4) {
        const float4 wv = *(const float4*)(w + j);
        const float4 xv = *(const float4*)(xt + j);
        acc += wv.x*xv.x + wv.y*xv.y + wv.z*xv.z + wv.w*xv.w;
      }
      spf[o*4 + part] = acc;
    }
    __syncthreads();
    if (tid < 81) {
      const float v = projb[tid] + spf[tid*4] + spf[tid*4+1] + spf[tid*4+2] + spf[tid*4+3];
      if (tid < 80) out_mel[(b*NMEL_ + tid)*T_ + (T_-1)] = v;
      else          out_stop[b*T_ + (T_-1)] = v;
    }
  }
}

extern "C" void kernel_launch(void* const* d_in, const int* in_sizes, int n_in,
                              void* d_out, int out_size, void* d_ws, size_t ws_size,
                              hipStream_t stream) {
  const float* mels  = (const float*)d_in[0];
  const float* enc   = (const float*)d_in[1];
  const int*   tlen  = (const int*)d_in[2];
  const float* Wt    = (const float*)d_in[3];
  const float* Wq    = (const float*)d_in[4];
  const float* wsc   = (const float*)d_in[5];
  const float* conv1 = (const float*)d_in[6];
  const float* conv2 = (const float*)d_in[7];
  const float* pW1   = (const float*)d_in[8];
  const float* pb1   = (const float*)d_in[9];
  const float* pW2   = (const float*)d_in[10];
  const float* pb2   = (const float*)d_in[11];
  const float* Wih0  = (const float*)d_in[12];
  const float* Whh0  = (const float*)d_in[13];
  const float* bih0  = (const float*)d_in[14];
  const float* bhh0  = (const float*)d_in[15];
  const float* Wih1  = (const float*)d_in[16];
  const float* Whh1  = (const float*)d_in[17];
  const float* bih1  = (const float*)d_in[18];
  const float* bhh1  = (const float*)d_in[19];
  const float* h0    = (const float*)d_in[20];
  const float* c0    = (const float*)d_in[21];
  const float* projW = (const float*)d_in[22];
  const float* projb = (const float*)d_in[23];

  float* ws     = (float*)d_ws;
  float* melpre = ws;                 // 300*16*256
  float* lencb  = melpre + 1228800;   // 16*160*128
  float* weff   = lencb + 327680;     // 128*32
  float* h1buf  = weff + 4096;        // 2*16*1024
  float* albuf  = h1buf + 32768;      // 2*16*512
  float* h0st   = albuf + 16384;      // 16*1024
  float* c0s    = h0st + 16384;       // 16*1024
  float* c1s    = c0s + 16384;        // 16*1024
  float* g0pre  = c1s + 16384;        // 16*4096
  float* g1pre  = g0pre + 65536;      // 16*4096
  u32*   bar    = (u32*)(g1pre + 65536); // 16 u32 barrier words

  float* out_mel  = (float*)d_out;
  float* out_stop = out_mel + 384000;
  float* out_attn = out_stop + 4800;

  prenet_kernel<<<dim3(480), dim3(256), 0, stream>>>(mels, pW1, pb1, pW2, pb2, melpre);
  init_kernel<<<dim3(80), dim3(256), 0, stream>>>(h0, c0, conv1, conv2, h1buf, h0st, c0s, c1s, weff, bar);
  lenc_kernel<<<dim3(640), dim3(256), 0, stream>>>(enc, Wt, lencb);

  void* args[] = {
    (void*)&melpre, (void*)&lencb, (void*)&weff, (void*)&h1buf, (void*)&albuf,
    (void*)&h0st, (void*)&c0s, (void*)&c1s, (void*)&g0pre, (void*)&g1pre, (void*)&bar,
    (void*)&enc, (void*)&tlen, (void*)&Wq, (void*)&wsc,
    (void*)&Wih0, (void*)&Whh0, (void*)&bih0, (void*)&bhh0,
    (void*)&Wih1, (void*)&Whh1, (void*)&bih1, (void*)&bhh1,
    (void*)&projW, (void*)&projb,
    (void*)&out_mel, (void*)&out_stop, (void*)&out_attn
  };
  hipLaunchCooperativeKernel((const void*)decoder_kernel, dim3(256), dim3(512),
                             args, (unsigned int)(B_*XSTR*sizeof(float)), stream);
}

// Round 4
// 48081.473 us; speedup vs baseline: 2.0658x; 1.3809x over previous
//
#include <hip/hip_runtime.h>

#define T_    300
#define B_    16
#define S_    160
#define NMEL_ 80
#define PRE_  256
#define ENC_  512
#define ATT_  128
#define DIM_  1024

#define XST1  1288     // P1 tile stride (mel 256 + h0 1024 + pad 8)
#define XST2  520      // P2 align tile stride
#define XST3  1032     // P3 h0 tile stride
#define WOFF  16704    // attn blocks: weff copy lives at xt[WOFF..WOFF+4096)
#define XTOT  20800    // dynamic LDS floats (83.2 KB)
#define BARWORDS 17408

typedef unsigned int u32;

__device__ __forceinline__ float fexp2f(float x) { return __builtin_amdgcn_exp2f(x); }
__device__ __forceinline__ float fsigf(float x)  { return 1.0f / (1.0f + fexp2f(-1.442695041f * x)); }
__device__ __forceinline__ float ftanhf(float x) {
  float xc = fminf(fmaxf(x, -15.0f), 15.0f);
  float e = fexp2f(2.885390082f * xc);
  return (e - 1.0f) / (e + 1.0f);
}

// ---- system-scope (LLC) accessors. waitcnt lives INSIDE each asm block so the
// register allocator never sees a pending-load destination (R3 bug).
__device__ __forceinline__ float4 ld1q_sys(const float* p) {
  float4 v;
  asm volatile("global_load_dwordx4 %0, %1, off sc0 sc1\n\ts_waitcnt vmcnt(0)"
               : "=v"(v) : "v"(p) : "memory");
  return v;
}
__device__ __forceinline__ void ld4q_sys(const float* p0, const float* p1,
                                         const float* p2, const float* p3,
                                         float4& a, float4& b, float4& c, float4& d) {
  asm volatile(
      "global_load_dwordx4 %0, %4, off sc0 sc1\n\t"
      "global_load_dwordx4 %1, %5, off sc0 sc1\n\t"
      "global_load_dwordx4 %2, %6, off sc0 sc1\n\t"
      "global_load_dwordx4 %3, %7, off sc0 sc1\n\t"
      "s_waitcnt vmcnt(0)"
      : "=&v"(a), "=&v"(b), "=&v"(c), "=&v"(d)
      : "v"(p0), "v"(p1), "v"(p2), "v"(p3) : "memory");
}
__device__ __forceinline__ void ld8q_sys(const float* p0,const float* p1,const float* p2,const float* p3,
                                         const float* p4,const float* p5,const float* p6,const float* p7,
                                         float4& a,float4& b,float4& c,float4& d,
                                         float4& e,float4& f,float4& g,float4& h) {
  asm volatile(
      "global_load_dwordx4 %0, %8, off sc0 sc1\n\t"
      "global_load_dwordx4 %1, %9, off sc0 sc1\n\t"
      "global_load_dwordx4 %2, %10, off sc0 sc1\n\t"
      "global_load_dwordx4 %3, %11, off sc0 sc1\n\t"
      "global_load_dwordx4 %4, %12, off sc0 sc1\n\t"
      "global_load_dwordx4 %5, %13, off sc0 sc1\n\t"
      "global_load_dwordx4 %6, %14, off sc0 sc1\n\t"
      "global_load_dwordx4 %7, %15, off sc0 sc1\n\t"
      "s_waitcnt vmcnt(0)"
      : "=&v"(a),"=&v"(b),"=&v"(c),"=&v"(d),"=&v"(e),"=&v"(f),"=&v"(g),"=&v"(h)
      : "v"(p0),"v"(p1),"v"(p2),"v"(p3),"v"(p4),"v"(p5),"v"(p6),"v"(p7)
      : "memory");
}
__device__ __forceinline__ void st_sys(float* p, float v) {
  asm volatile("global_store_dword %0, %1, off sc0 sc1" :: "v"(p), "v"(v) : "memory");
}
__device__ __forceinline__ u32 ld_sys_u32(const u32* p) {
  u32 r;
  asm volatile("global_load_dword %0, %1, off sc0 sc1\n\ts_waitcnt vmcnt(0)"
               : "=v"(r) : "v"(p) : "memory");
  return r;
}
__device__ __forceinline__ void st_sys_u32(u32* p, u32 v) {
  asm volatile("global_store_dword %0, %1, off sc0 sc1" :: "v"(p), "v"(v) : "memory");
}

// ---- tree barrier: 16 groups x 16 blocks, counters/releases 4KB apart, epoch-based.
__device__ __forceinline__ void gridbar(u32* bar, int tid, int blk, u32 ep) {
  asm volatile("s_waitcnt vmcnt(0)" ::: "memory");   // drain this wave's sc stores
  __syncthreads();
  if (tid == 0) {
    const int g = blk & 15;
    u32* cnt  = bar + g*1024;
    u32* grel = bar + g*1024 + 64;
    u32* tcnt = bar + 16384;
    u32* trel = bar + 16384 + 64;
    const u32 tgt = ep*16u + 15u;
    u32 old = __hip_atomic_fetch_add(cnt, 1u, __ATOMIC_RELAXED, __HIP_MEMORY_SCOPE_AGENT);
    if (old == tgt) {
      u32 told = __hip_atomic_fetch_add(tcnt, 1u, __ATOMIC_RELAXED, __HIP_MEMORY_SCOPE_AGENT);
      if (told == tgt) {
        st_sys_u32(trel, ep + 1u);
      } else {
        while (ld_sys_u32(trel) != ep + 1u) __builtin_amdgcn_s_sleep(2);
      }
      st_sys_u32(grel, ep + 1u);
    } else {
      while (ld_sys_u32(grel) != ep + 1u) __builtin_amdgcn_s_sleep(2);
    }
  }
  __syncthreads();
}

#define REDUCE64(v) do { \
  v += __shfl_down(v, 32, 64); v += __shfl_down(v, 16, 64); v += __shfl_down(v, 8, 64); \
  v += __shfl_down(v, 4, 64);  v += __shfl_down(v, 2, 64);  v += __shfl_down(v, 1, 64); } while (0)

// ---------------- prenet
__launch_bounds__(256)
__global__ void prenet_kernel(const float* __restrict__ mels,
                              const float* __restrict__ pW1, const float* __restrict__ pb1,
                              const float* __restrict__ pW2, const float* __restrict__ pb2,
                              float* __restrict__ melpre) {
  __shared__ float mcol[NMEL_];
  __shared__ float pcol[PRE_];
  const int b = blockIdx.x / 30;
  const int tbase = (blockIdx.x % 30) * 10;
  const int tid = threadIdx.x;
  for (int f = 0; f < 10; ++f) {
    const int t = tbase + f;
    if (tid < NMEL_) mcol[tid] = (t == 0) ? 0.0f : mels[(b*NMEL_ + tid)*T_ + (t-1)];
    __syncthreads();
    {
      float a1 = pb1[tid];
      const float* w1 = pW1 + tid*NMEL_;
      for (int m = 0; m < NMEL_; ++m) a1 += w1[m]*mcol[m];
      pcol[tid] = fmaxf(a1, 0.0f);
    }
    __syncthreads();
    {
      float a2 = pb2[tid];
      const float* w2 = pW2 + tid*PRE_;
      for (int d = 0; d < PRE_; d += 4) {
        const float4 wv = *(const float4*)(w2 + d);
        a2 += wv.x*pcol[d] + wv.y*pcol[d+1] + wv.z*pcol[d+2] + wv.w*pcol[d+3];
      }
      melpre[(t*B_ + b)*PRE_ + tid] = fmaxf(a2, 0.0f);
    }
    __syncthreads();
  }
}

// ---------------- init: h states, Weff, barrier region
__launch_bounds__(256)
__global__ void init_kernel(const float* __restrict__ h0,
                            const float* __restrict__ conv1, const float* __restrict__ conv2,
                            float* __restrict__ h1buf, float* __restrict__ h0st,
                            float* __restrict__ weff, u32* __restrict__ bar) {
  const int idx = blockIdx.x*256 + threadIdx.x;
  if (idx < B_*DIM_) {
    const int j = idx & (DIM_-1);
    h0st[idx]  = h0[j];
    h1buf[idx] = h0[DIM_ + j];
  } else if (idx < B_*DIM_ + ATT_*32) {
    const int r = idx - B_*DIM_;
    const int a = r >> 5, k = r & 31;
    float acc = 0.0f;
    if (k < 31) {
      for (int l = 0; l < 32; ++l) acc += conv2[a*32 + l]*conv1[l*31 + k];
    }
    weff[r] = acc;
  } else if (idx < B_*DIM_ + ATT_*32 + BARWORDS) {
    bar[idx - (B_*DIM_ + ATT_*32)] = 0u;
  }
}

// ---------------- l_enc
__launch_bounds__(256)
__global__ void lenc_kernel(const float* __restrict__ enc, const float* __restrict__ Wt,
                            float* __restrict__ lencb) {
  __shared__ float es[4*ENC_];
  const int b = blockIdx.x / 40;
  const int s0 = (blockIdx.x % 40) * 4;
  const int tid = threadIdx.x;
  for (int idx = tid; idx < 4*ENC_; idx += 256) es[idx] = enc[(b*S_ + s0)*ENC_ + idx];
  __syncthreads();
  const int a = tid & 127, sh = tid >> 7;
  const float* w = Wt + a*ENC_;
  for (int p = 0; p < 2; ++p) {
    const int sl = sh*2 + p;
    const float* e = es + sl*ENC_;
    float acc = 0.0f;
    for (int j = 0; j < ENC_; j += 4) {
      const float4 wv = *(const float4*)(w + j);
      acc += wv.x*e[j] + wv.y*e[j+1] + wv.z*e[j+2] + wv.w*e[j+3];
    }
    lencb[(b*S_ + s0 + sl)*ATT_ + a] = acc;
  }
}

// ---------------- persistent decoder
// block blk owns j-columns j0=blk*4 in P2/P3 (LSTM assembly + activation).
// P1: blk<16 attention; blk>=16: own gates0-pre & gates1-pre in LDS (gv0/gv1);
//     blocks 16..79 / 80..143 additionally produce the attn blocks' pre-slots (g0pre/g1pre).
// P2: align part of gates0 + LSTM0 -> h0st
// P3: Wih1@h0 + LSTM1 -> h1buf; attn blocks also project step t-1.
__launch_bounds__(512, 2)
__global__ void decoder_kernel(
    const float* __restrict__ melpre, const float* __restrict__ lencb,
    const float* __restrict__ weff,
    float* __restrict__ h1buf, float* __restrict__ albuf, float* __restrict__ h0st,
    float* __restrict__ g0pre, float* __restrict__ g1pre, u32* __restrict__ bar,
    const float* __restrict__ enc, const int* __restrict__ tlen,
    const float* __restrict__ Wq, const float* __restrict__ wsc,
    const float* __restrict__ Wih0, const float* __restrict__ Whh0,
    const float* __restrict__ bih0, const float* __restrict__ bhh0,
    const float* __restrict__ Wih1, const float* __restrict__ Whh1,
    const float* __restrict__ bih1, const float* __restrict__ bhh1,
    const float* __restrict__ c0in, const float* __restrict__ projW, const float* __restrict__ projb,
    float* __restrict__ out_mel, float* __restrict__ out_stop, float* __restrict__ out_attn)
{
  extern __shared__ float xt[];
  __shared__ float cum_p[S_ + 30];
  __shared__ float q_s[ATT_];
  __shared__ float spf[S_*4];
  __shared__ float score_s[S_];
  __shared__ float attn_s[S_];
  __shared__ float red_s[1];
  __shared__ float gv[256];    // P2/P3 GEMV reduction
  __shared__ float gv0[256];   // gates0 pre (own rows), persists P1->P2
  __shared__ float gv1[256];   // gates1 pre (own rows), persists P1->P3
  __shared__ float projx[1536];
  __shared__ float wscs[ATT_];

  const int blk = blockIdx.x;
  const int tid = threadIdx.x;
  const int ks = tid & 63;
  const int bgb = ((tid >> 6) & 1)*8;
  const int rg = tid >> 7;
  const int j0 = blk*4;

  // per-block persistent cell state in registers (lanes tid<64)
  float c0r = 0.0f, c1r = 0.0f;
  if (tid < 64) {
    const int j = j0 + (tid >> 4);
    c0r = c0in[j];
    c1r = c0in[DIM_ + j];
  }
  int mylen = 0;
  if (blk < B_) {
    mylen = tlen[blk];
    for (int i = tid; i < S_ + 30; i += 512) cum_p[i] = 0.0f;
    for (int i = tid; i < 4096; i += 512) xt[WOFF + i] = weff[i];
    if (tid < ATT_) wscs[tid] = wsc[tid];
  }
  __syncthreads();

  u32 ep = 0;

  for (int t = 0; t < T_; ++t) {
    const int prev = t & 1;
    const int cur = prev ^ 1;

    //====================== P1 ======================
    if (blk < B_) {
      const int b = blk;
      // stage [h1prev | alignprev] into projx (used for q now, proj in P3)
      if (tid < 256) {
        float4 v = ld1q_sys(h1buf + prev*B_*DIM_ + b*DIM_ + tid*4);
        *(float4*)(projx + tid*4) = v;
      } else if (tid < 384) {
        const int j = tid - 256;
        float4 v = ld1q_sys(albuf + prev*B_*ENC_ + b*ENC_ + j*4);
        *(float4*)(projx + 1024 + j*4) = v;
      }
      __syncthreads();
      // q = h1prev @ Wq^T
      {
        const int a = tid & 127, part = tid >> 7;
        const float* hp = projx + part*256;
        const float* wq = Wq + a*DIM_ + part*256;
        float acc = 0.0f;
        for (int j = 0; j < 256; j += 4) {
          const float4 wv = *(const float4*)(wq + j);
          const float4 hv = *(const float4*)(hp + j);
          acc += wv.x*hv.x + wv.y*hv.y + wv.z*hv.z + wv.w*hv.w;
        }
        spf[a*4 + part] = acc;
      }
      __syncthreads();
      if (tid < ATT_) q_s[tid] = spf[tid*4] + spf[tid*4+1] + spf[tid*4+2] + spf[tid*4+3];
      __syncthreads();
      // scores
      {
        const int sl = tid & 127, ag = tid >> 7;
        #pragma unroll
        for (int p = 0; p < 2; ++p) {
          const int s = sl + p*128;
          if (s < S_) {
            float cw[31];
            #pragma unroll
            for (int k = 0; k < 31; ++k) cw[k] = cum_p[s + k];
            const float* le = lencb + (b*S_ + s)*ATT_ + ag*32;
            float ps = 0.0f;
            for (int i = 0; i < 32; ++i) {
              const int a = ag*32 + i;
              const float* wk = xt + WOFF + a*32;
              float loc = 0.0f;
              #pragma unroll
              for (int k = 0; k < 31; ++k) loc += wk[k]*cw[k];
              ps += wscs[a]*ftanhf(q_s[a] + le[i] + loc);
            }
            spf[s*4 + ag] = ps;
          }
        }
      }
      __syncthreads();
      if (tid < S_) {
        float sc = spf[tid*4] + spf[tid*4+1] + spf[tid*4+2] + spf[tid*4+3];
        if (tid >= mylen) sc = -1.0e30f;
        score_s[tid] = sc;
      }
      __syncthreads();
      if (tid < 64) {
        float m = -1.0e30f;
        for (int i = tid; i < S_; i += 64) m = fmaxf(m, score_s[i]);
        #pragma unroll
        for (int o = 32; o > 0; o >>= 1) m = fmaxf(m, __shfl_xor(m, o, 64));
        float sum = 0.0f;
        for (int i = tid; i < S_; i += 64) {
          const float e = fexp2f(1.442695041f*(score_s[i] - m));
          score_s[i] = e;
          sum += e;
        }
        #pragma unroll
        for (int o = 32; o > 0; o >>= 1) sum += __shfl_xor(sum, o, 64);
        if (tid == 0) red_s[0] = sum;
      }
      __syncthreads();
      {
        const float inv = 1.0f / red_s[0];
        if (tid < S_) {
          const float av = score_s[tid]*inv;
          attn_s[tid] = av;
          cum_p[15 + tid] += av;
          out_attn[(b*S_ + tid)*T_ + t] = av;
        }
      }
      __syncthreads();
      // align = attn @ enc  -> albuf[cur] (sc)
      {
        const float* eb = enc + (b*S_)*ENC_ + tid;
        float acc = 0.0f;
        for (int s = 0; s < S_; ++s) acc += attn_s[s]*eb[s*ENC_];
        st_sys(albuf + cur*B_*ENC_ + b*ENC_ + tid, acc);
      }
    } else {
      const bool hg0 = (blk >= 16 && blk < 80);
      const bool hg1 = (blk >= 80 && blk < 144);
      const int jx0 = blk - 16;
      const int jx1 = blk - 80;
      // ---- stage [mel | h0prev] tile
      for (int i = tid; i < 1024; i += 512) {
        float4 v = *(const float4*)(melpre + t*4096 + i*4);
        *(float4*)(xt + (i>>6)*XST1 + (i&63)*4) = v;
      }
      {
        float4 r0,r1,r2,r3,r4,r5,r6,r7;
        ld8q_sys(h0st + tid*4, h0st + (tid+512)*4, h0st + (tid+1024)*4, h0st + (tid+1536)*4,
                 h0st + (tid+2048)*4, h0st + (tid+2560)*4, h0st + (tid+3072)*4, h0st + (tid+3584)*4,
                 r0,r1,r2,r3,r4,r5,r6,r7);
        *(float4*)(xt + ((tid       )>>8)*XST1 + 256 + ((tid       )&255)*4) = r0;
        *(float4*)(xt + ((tid + 512 )>>8)*XST1 + 256 + ((tid + 512 )&255)*4) = r1;
        *(float4*)(xt + ((tid + 1024)>>8)*XST1 + 256 + ((tid + 1024)&255)*4) = r2;
        *(float4*)(xt + ((tid + 1536)>>8)*XST1 + 256 + ((tid + 1536)&255)*4) = r3;
        *(float4*)(xt + ((tid + 2048)>>8)*XST1 + 256 + ((tid + 2048)&255)*4) = r4;
        *(float4*)(xt + ((tid + 2560)>>8)*XST1 + 256 + ((tid + 2560)&255)*4) = r5;
        *(float4*)(xt + ((tid + 3072)>>8)*XST1 + 256 + ((tid + 3072)&255)*4) = r6;
        *(float4*)(xt + ((tid + 3584)>>8)*XST1 + 256 + ((tid + 3584)&255)*4) = r7;
      }
      __syncthreads();
      // ---- GEMV-a: gates0 pre = Wih0[:, :256]@mel + Whh0@h0prev (+biases)
      {
        const int nr = hg0 ? 5 : 4;
        int nrow[5];
        #pragma unroll
        for (int ri = 0; ri < 4; ++ri) nrow[ri] = ri*1024 + j0 + rg;
        nrow[4] = rg*1024 + ((jx0 < 64) ? jx0 : 0);
        float acc[5][8];
        #pragma unroll
        for (int ri = 0; ri < 5; ++ri)
          #pragma unroll
          for (int bi = 0; bi < 8; ++bi) acc[ri][bi] = 0.0f;
        { // mel chunk
          const int j = ks*4;
          float4 w4[5];
          #pragma unroll
          for (int ri = 0; ri < 5; ++ri)
            if (ri < nr) w4[ri] = *(const float4*)(Wih0 + nrow[ri]*768 + j);
          #pragma unroll
          for (int bi = 0; bi < 8; ++bi) {
            const float4 xv = *(const float4*)(xt + (bgb+bi)*XST1 + j);
            #pragma unroll
            for (int ri = 0; ri < 5; ++ri)
              if (ri < nr)
                acc[ri][bi] += w4[ri].x*xv.x + w4[ri].y*xv.y + w4[ri].z*xv.z + w4[ri].w*xv.w;
          }
        }
        #pragma unroll
        for (int q = 0; q < 4; ++q) { // h0 chunks
          const int j = q*256 + ks*4;
          float4 w4[5];
          #pragma unroll
          for (int ri = 0; ri < 5; ++ri)
            if (ri < nr) w4[ri] = *(const float4*)(Whh0 + nrow[ri]*1024 + j);
          #pragma unroll
          for (int bi = 0; bi < 8; ++bi) {
            const float4 xv = *(const float4*)(xt + (bgb+bi)*XST1 + 256 + j);
            #pragma unroll
            for (int ri = 0; ri < 5; ++ri)
              if (ri < nr)
                acc[ri][bi] += w4[ri].x*xv.x + w4[ri].y*xv.y + w4[ri].z*xv.z + w4[ri].w*xv.w;
          }
        }
        #pragma unroll
        for (int ri = 0; ri < 5; ++ri)
          if (ri < nr)
            #pragma unroll
            for (int bi = 0; bi < 8; ++bi) {
              float v = acc[ri][bi];
              REDUCE64(v);
              if (ks == 0) {
                const int n = nrow[ri];
                v += bih0[n] + bhh0[n];
                if (ri < 4) gv0[(ri*4 + rg)*16 + (bgb+bi)] = v;
                else        st_sys(g0pre + (bgb+bi)*256 + jx0*4 + rg, v);
              }
            }
      }
      __syncthreads();
      // ---- stage h1prev tile (waited batched LLC load)
      {
        const float* src = h1buf + prev*B_*DIM_;
        float4 r0,r1,r2,r3,r4,r5,r6,r7;
        ld8q_sys(src + tid*4, src + (tid+512)*4, src + (tid+1024)*4, src + (tid+1536)*4,
                 src + (tid+2048)*4, src + (tid+2560)*4, src + (tid+3072)*4, src + (tid+3584)*4,
                 r0,r1,r2,r3,r4,r5,r6,r7);
        *(float4*)(xt + ((tid       )>>8)*XST1 + ((tid       )&255)*4) = r0;
        *(float4*)(xt + ((tid + 512 )>>8)*XST1 + ((tid + 512 )&255)*4) = r1;
        *(float4*)(xt + ((tid + 1024)>>8)*XST1 + ((tid + 1024)&255)*4) = r2;
        *(float4*)(xt + ((tid + 1536)>>8)*XST1 + ((tid + 1536)&255)*4) = r3;
        *(float4*)(xt + ((tid + 2048)>>8)*XST1 + ((tid + 2048)&255)*4) = r4;
        *(float4*)(xt + ((tid + 2560)>>8)*XST1 + ((tid + 2560)&255)*4) = r5;
        *(float4*)(xt + ((tid + 3072)>>8)*XST1 + ((tid + 3072)&255)*4) = r6;
        *(float4*)(xt + ((tid + 3584)>>8)*XST1 + ((tid + 3584)&255)*4) = r7;
      }
      __syncthreads();
      // ---- GEMV-b: gates1 pre = Whh1@h1prev (+biases)
      {
        const int nr = hg1 ? 5 : 4;
        int nrow[5];
        #pragma unroll
        for (int ri = 0; ri < 4; ++ri) nrow[ri] = ri*1024 + j0 + rg;
        nrow[4] = rg*1024 + (hg1 ? jx1 : 0);
        float acc[5][8];
        #pragma unroll
        for (int ri = 0; ri < 5; ++ri)
          #pragma unroll
          for (int bi = 0; bi < 8; ++bi) acc[ri][bi] = 0.0f;
        #pragma unroll
        for (int q = 0; q < 4; ++q) {
          const int j = q*256 + ks*4;
          float4 w4[5];
          #pragma unroll
          for (int ri = 0; ri < 5; ++ri)
            if (ri < nr) w4[ri] = *(const float4*)(Whh1 + nrow[ri]*1024 + j);
          #pragma unroll
          for (int bi = 0; bi < 8; ++bi) {
            const float4 xv = *(const float4*)(xt + (bgb+bi)*XST1 + j);
            #pragma unroll
            for (int ri = 0; ri < 5; ++ri)
              if (ri < nr)
                acc[ri][bi] += w4[ri].x*xv.x + w4[ri].y*xv.y + w4[ri].z*xv.z + w4[ri].w*xv.w;
          }
        }
        #pragma unroll
        for (int ri = 0; ri < 5; ++ri)
          if (ri < nr)
            #pragma unroll
            for (int bi = 0; bi < 8; ++bi) {
              float v = acc[ri][bi];
              REDUCE64(v);
              if (ks == 0) {
                const int n = nrow[ri];
                v += bih1[n] + bhh1[n];
                if (ri < 4) gv1[(ri*4 + rg)*16 + (bgb+bi)] = v;
                else        st_sys(g1pre + (bgb+bi)*256 + jx1*4 + rg, v);
              }
            }
      }
    }
    gridbar(bar, tid, blk, ep); ++ep;

    //====================== P2: gates0 align part + LSTM0 ======================
    {
      { // stage align tile (waited)
        const float* src = albuf + cur*B_*ENC_;
        float4 r0,r1,r2,r3;
        ld4q_sys(src + tid*4, src + (tid+512)*4, src + (tid+1024)*4, src + (tid+1536)*4,
                 r0,r1,r2,r3);
        *(float4*)(xt + ((tid       )>>7)*XST2 + ((tid       )&127)*4) = r0;
        *(float4*)(xt + ((tid + 512 )>>7)*XST2 + ((tid + 512 )&127)*4) = r1;
        *(float4*)(xt + ((tid + 1024)>>7)*XST2 + ((tid + 1024)&127)*4) = r2;
        *(float4*)(xt + ((tid + 1536)>>7)*XST2 + ((tid + 1536)&127)*4) = r3;
      }
      __syncthreads();
      float acc[4][8];
      #pragma unroll
      for (int ri = 0; ri < 4; ++ri)
        #pragma unroll
        for (int bi = 0; bi < 8; ++bi) acc[ri][bi] = 0.0f;
      #pragma unroll
      for (int q = 0; q < 2; ++q) {
        const int j = q*256 + ks*4;
        float4 w4[4];
        #pragma unroll
        for (int ri = 0; ri < 4; ++ri)
          w4[ri] = *(const float4*)(Wih0 + (ri*1024 + j0 + rg)*768 + 256 + j);
        #pragma unroll
        for (int bi = 0; bi < 8; ++bi) {
          const float4 xv = *(const float4*)(xt + (bgb+bi)*XST2 + j);
          #pragma unroll
          for (int ri = 0; ri < 4; ++ri)
            acc[ri][bi] += w4[ri].x*xv.x + w4[ri].y*xv.y + w4[ri].z*xv.z + w4[ri].w*xv.w;
        }
      }
      #pragma unroll
      for (int ri = 0; ri < 4; ++ri)
        #pragma unroll
        for (int bi = 0; bi < 8; ++bi) {
          float v = acc[ri][bi];
          REDUCE64(v);
          if (ks == 0) gv[(rg*4 + ri)*16 + (bgb+bi)] = v;
        }
      __syncthreads();
      if (tid < 64) {
        const int jl = tid >> 4, bb = tid & 15;
        const int j = j0 + jl;
        float pi, pf, pg, po;
        if (blk < B_) {
          const float4 g4 = ld1q_sys(g0pre + bb*256 + j*4);
          pi = g4.x; pf = g4.y; pg = g4.z; po = g4.w;
        } else {
          pi = gv0[(0*4 + jl)*16 + bb];
          pf = gv0[(1*4 + jl)*16 + bb];
          pg = gv0[(2*4 + jl)*16 + bb];
          po = gv0[(3*4 + jl)*16 + bb];
        }
        const float gi = gv[(jl*4+0)*16 + bb] + pi;
        const float gf = gv[(jl*4+1)*16 + bb] + pf;
        const float gg = gv[(jl*4+2)*16 + bb] + pg;
        const float go = gv[(jl*4+3)*16 + bb] + po;
        const float cn = fsigf(gf)*c0r + fsigf(gi)*ftanhf(gg);
        const float hn = fsigf(go)*ftanhf(cn);
        c0r = cn;
        st_sys(h0st + bb*DIM_ + j, hn);
      }
    }
    gridbar(bar, tid, blk, ep); ++ep;

    //====================== P3: gates1 Wih1@h0 + LSTM1 (+proj for attn blocks) ======================
    {
      { // stage h0 tile (waited batched)
        float4 r0,r1,r2,r3,r4,r5,r6,r7;
        ld8q_sys(h0st + tid*4, h0st + (tid+512)*4, h0st + (tid+1024)*4, h0st + (tid+1536)*4,
                 h0st + (tid+2048)*4, h0st + (tid+2560)*4, h0st + (tid+3072)*4, h0st + (tid+3584)*4,
                 r0,r1,r2,r3,r4,r5,r6,r7);
        *(float4*)(xt + ((tid       )>>8)*XST3 + ((tid       )&255)*4) = r0;
        *(float4*)(xt + ((tid + 512 )>>8)*XST3 + ((tid + 512 )&255)*4) = r1;
        *(float4*)(xt + ((tid + 1024)>>8)*XST3 + ((tid + 1024)&255)*4) = r2;
        *(float4*)(xt + ((tid + 1536)>>8)*XST3 + ((tid + 1536)&255)*4) = r3;
        *(float4*)(xt + ((tid + 2048)>>8)*XST3 + ((tid + 2048)&255)*4) = r4;
        *(float4*)(xt + ((tid + 2560)>>8)*XST3 + ((tid + 2560)&255)*4) = r5;
        *(float4*)(xt + ((tid + 3072)>>8)*XST3 + ((tid + 3072)&255)*4) = r6;
        *(float4*)(xt + ((tid + 3584)>>8)*XST3 + ((tid + 3584)&255)*4) = r7;
      }
      __syncthreads();
      float acc[4][8];
      #pragma unroll
      for (int ri = 0; ri < 4; ++ri)
        #pragma unroll
        for (int bi = 0; bi < 8; ++bi) acc[ri][bi] = 0.0f;
      #pragma unroll
      for (int q = 0; q < 4; ++q) {
        const int j = q*256 + ks*4;
        float4 w4[4];
        #pragma unroll
        for (int ri = 0; ri < 4; ++ri)
          w4[ri] = *(const float4*)(Wih1 + (ri*1024 + j0 + rg)*1024 + j);
        #pragma unroll
        for (int bi = 0; bi < 8; ++bi) {
          const float4 xv = *(const float4*)(xt + (bgb+bi)*XST3 + j);
          #pragma unroll
          for (int ri = 0; ri < 4; ++ri)
            acc[ri][bi] += w4[ri].x*xv.x + w4[ri].y*xv.y + w4[ri].z*xv.z + w4[ri].w*xv.w;
        }
      }
      #pragma unroll
      for (int ri = 0; ri < 4; ++ri)
        #pragma unroll
        for (int bi = 0; bi < 8; ++bi) {
          float v = acc[ri][bi];
          REDUCE64(v);
          if (ks == 0) gv[(rg*4 + ri)*16 + (bgb+bi)] = v;
        }
      __syncthreads();
      if (tid < 64) {
        const int jl = tid >> 4, bb = tid & 15;
        const int j = j0 + jl;
        float pi, pf, pg, po;
        if (blk < B_) {
          const float4 g4 = ld1q_sys(g1pre + bb*256 + j*4);
          pi = g4.x; pf = g4.y; pg = g4.z; po = g4.w;
        } else {
          pi = gv1[(0*4 + jl)*16 + bb];
          pf = gv1[(1*4 + jl)*16 + bb];
          pg = gv1[(2*4 + jl)*16 + bb];
          po = gv1[(3*4 + jl)*16 + bb];
        }
        const float gi = gv[(jl*4+0)*16 + bb] + pi;
        const float gf = gv[(jl*4+1)*16 + bb] + pf;
        const float gg = gv[(jl*4+2)*16 + bb] + pg;
        const float go = gv[(jl*4+3)*16 + bb] + po;
        const float cn = fsigf(gf)*c1r + fsigf(gi)*ftanhf(gg);
        const float hn = fsigf(go)*ftanhf(cn);
        c1r = cn;
        st_sys(h1buf + cur*B_*DIM_ + bb*DIM_ + j, hn);
      }
      // projection of step t-1 (attn blocks; inputs staged in projx during P1)
      if (blk < B_ && t > 0) {
        const int b = blk;
        const int o = tid >> 2, part = tid & 3;
        if (o < 81) {
          const float* w = projW + o*1536;
          const int jb = part*384;
          float acc2 = 0.0f;
          for (int j = jb; j < jb + 384; j += 4) {
            const float4 wv = *(const float4*)(w + j);
            const float4 xv = *(const float4*)(projx + j);
            acc2 += wv.x*xv.x + wv.y*xv.y + wv.z*xv.z + wv.w*xv.w;
          }
          spf[o*4 + part] = acc2;
        }
        __syncthreads();
        if (tid < 81) {
          const float v = projb[tid] + spf[tid*4] + spf[tid*4+1] + spf[tid*4+2] + spf[tid*4+3];
          if (tid < 80) out_mel[(b*NMEL_ + tid)*T_ + (t-1)] = v;
          else          out_stop[b*T_ + (t-1)] = v;
        }
      }
    }
    gridbar(bar, tid, blk, ep); ++ep;
  }

  // ---- tail projection for t = T_-1 (step-299 h1/align live in slot 0)
  if (blk < B_) {
    const int b = blk;
    if (tid < 256) {
      float4 v = ld1q_sys(h1buf + b*DIM_ + tid*4);
      *(float4*)(projx + tid*4) = v;
    } else if (tid < 384) {
      const int j = tid - 256;
      float4 v = ld1q_sys(albuf + b*ENC_ + j*4);
      *(float4*)(projx + 1024 + j*4) = v;
    }
    __syncthreads();
    const int o = tid >> 2, part = tid & 3;
    if (o < 81) {
      const float* w = projW + o*1536;
      const int jb = part*384;
      float acc = 0.0f;
      for (int j = jb; j < jb + 384; j += 4) {
        const float4 wv = *(const float4*)(w + j);
        const float4 xv = *(const float4*)(projx + j);
        acc += wv.x*xv.x + wv.y*xv.y + wv.z*xv.z + wv.w*xv.w;
      }
      spf[o*4 + part] = acc;
    }
    __syncthreads();
    if (tid < 81) {
      const float v = projb[tid] + spf[tid*4] + spf[tid*4+1] + spf[tid*4+2] + spf[tid*4+3];
      if (tid < 80) out_mel[(b*NMEL_ + tid)*T_ + (T_-1)] = v;
      else          out_stop[b*T_ + (T_-1)] = v;
    }
  }
}

extern "C" void kernel_launch(void* const* d_in, const int* in_sizes, int n_in,
                              void* d_out, int out_size, void* d_ws, size_t ws_size,
                              hipStream_t stream) {
  const float* mels  = (const float*)d_in[0];
  const float* enc   = (const float*)d_in[1];
  const int*   tlen  = (const int*)d_in[2];
  const float* Wt    = (const float*)d_in[3];
  const float* Wq    = (const float*)d_in[4];
  const float* wsc   = (const float*)d_in[5];
  const float* conv1 = (const float*)d_in[6];
  const float* conv2 = (const float*)d_in[7];
  const float* pW1   = (const float*)d_in[8];
  const float* pb1   = (const float*)d_in[9];
  const float* pW2   = (const float*)d_in[10];
  const float* pb2   = (const float*)d_in[11];
  const float* Wih0  = (const float*)d_in[12];
  const float* Whh0  = (const float*)d_in[13];
  const float* bih0  = (const float*)d_in[14];
  const float* bhh0  = (const float*)d_in[15];
  const float* Wih1  = (const float*)d_in[16];
  const float* Whh1  = (const float*)d_in[17];
  const float* bih1  = (const float*)d_in[18];
  const float* bhh1  = (const float*)d_in[19];
  const float* h0    = (const float*)d_in[20];
  const float* c0    = (const float*)d_in[21];
  const float* projW = (const float*)d_in[22];
  const float* projb = (const float*)d_in[23];

  float* ws     = (float*)d_ws;
  float* melpre = ws;                  // 300*16*256   = 1228800
  float* lencb  = melpre + 1228800;    // 16*160*128   = 327680
  float* weff   = lencb + 327680;      // 128*32       = 4096
  float* h1buf  = weff + 4096;         // 2*16*1024    = 32768
  float* albuf  = h1buf + 32768;       // 2*16*512     = 16384
  float* h0st   = albuf + 16384;       // 16*1024      = 16384
  float* g0pre  = h0st + 16384;        // 16*256       = 4096
  float* g1pre  = g0pre + 4096;        // 16*256       = 4096
  u32*   bar    = (u32*)(g1pre + 4096);// 17408 words

  float* out_mel  = (float*)d_out;
  float* out_stop = out_mel + 384000;
  float* out_attn = out_stop + 4800;

  prenet_kernel<<<dim3(480), dim3(256), 0, stream>>>(mels, pW1, pb1, pW2, pb2, melpre);
  init_kernel<<<dim3(160), dim3(256), 0, stream>>>(h0, conv1, conv2, h1buf, h0st, weff, bar);
  lenc_kernel<<<dim3(640), dim3(256), 0, stream>>>(enc, Wt, lencb);

  void* args[] = {
    (void*)&melpre, (void*)&lencb, (void*)&weff, (void*)&h1buf, (void*)&albuf, (void*)&h0st,
    (void*)&g0pre, (void*)&g1pre, (void*)&bar,
    (void*)&enc, (void*)&tlen, (void*)&Wq, (void*)&wsc,
    (void*)&Wih0, (void*)&Whh0, (void*)&bih0, (void*)&bhh0,
    (void*)&Wih1, (void*)&Whh1, (void*)&bih1, (void*)&bhh1,
    (void*)&c0, (void*)&projW, (void*)&projb,
    (void*)&out_mel, (void*)&out_stop, (void*)&out_attn
  };
  hipLaunchCooperativeKernel((const void*)decoder_kernel, dim3(256), dim3(512),
                             args, (unsigned int)(XTOT*sizeof(float)), stream);
}